// Round 2
// baseline (553.963 us; speedup 1.0000x reference)
//
#include <hip/hip_runtime.h>
#include <hip/hip_bf16.h>
#include <stdint.h>

// Problem constants (reference: B,TQ,TK,D,DV = 8,2048,2048,1024,1024)
#define B_  8
#define TQ_ 2048
#define TK_ 2048
#define D_  1024
#define DV_ 1024

typedef __attribute__((ext_vector_type(8))) short  short8;
typedef __attribute__((ext_vector_type(4))) float  floatx4;

__device__ __forceinline__ void async_copy16(const void* g, void* l) {
  // 16B-per-lane global->LDS DMA. LDS dest is wave-uniform base + lane*16.
  __builtin_amdgcn_global_load_lds(
      (const __attribute__((address_space(1))) unsigned int*)g,
      (__attribute__((address_space(3))) unsigned int*)l,
      16, 0, 0);
}

__device__ __forceinline__ ushort f2bf(float f) {
  union { __hip_bfloat16 b; ushort u; } cv;
  cv.b = __float2bfloat16(f);
  return cv.u;
}

__device__ __forceinline__ float bf2f(ushort u) {
  union { ushort u; __hip_bfloat16 b; } cv;
  cv.u = u;
  return __bfloat162float(cv.b);
}

// ---------------- conversion kernels ----------------

// fp32 -> bf16, same layout, 4 elems/thread
__global__ void cvt_bf16(const float4* __restrict__ in, ushort4* __restrict__ out, int n4) {
  int i = blockIdx.x * 256 + threadIdx.x;
  if (i < n4) {
    float4 f = in[i];
    ushort4 o;
    o.x = f2bf(f.x); o.y = f2bf(f.y); o.z = f2bf(f.z); o.w = f2bf(f.w);
    out[i] = o;
  }
}

// in: [z][R][C] fp32 -> out: [z][C][R] bf16. 64x64 tiles, float4 loads,
// ushort4 stores (round-1's scalar ushort stores were 64B/wave-instr).
__global__ void transpose_cvt64(const float* __restrict__ in, ushort* __restrict__ out,
                                int R, int C) {
  __shared__ float tile[64][65];
  const int t  = threadIdx.x;            // 256
  const int c0 = blockIdx.x * 64, r0 = blockIdx.y * 64;
  const size_t z = (size_t)blockIdx.z * R * C;
  {
    const int row = t >> 4, col = (t & 15) * 4;
    #pragma unroll
    for (int ro = 0; ro < 4; ro++) {
      const float4 f = *(const float4*)&in[z + (size_t)(r0 + ro * 16 + row) * C + c0 + col];
      tile[ro * 16 + row][col + 0] = f.x;
      tile[ro * 16 + row][col + 1] = f.y;
      tile[ro * 16 + row][col + 2] = f.z;
      tile[ro * 16 + row][col + 3] = f.w;
    }
  }
  __syncthreads();
  {
    const int c = t >> 4, rg = (t & 15) * 4;
    #pragma unroll
    for (int ro = 0; ro < 4; ro++) {
      const int cc = ro * 16 + c;
      ushort4 o;
      o.x = f2bf(tile[rg + 0][cc]);
      o.y = f2bf(tile[rg + 1][cc]);
      o.z = f2bf(tile[rg + 2][cc]);
      o.w = f2bf(tile[rg + 3][cc]);
      *(ushort4*)&out[z + (size_t)(c0 + cc) * R + r0 + rg] = o;
    }
  }
}

// ---------------- GEMM core (BK=64, XOR-swizzled staging) ----------------
// C[128x128]/block, 256 thr = 4 waves 2x2, each wave 64x64 = 4x4 tiles of
// mfma_f32_16x16x32_bf16, 2 k-substeps per K-step -> 32 MFMA per barrier pair.
// A: [M][KDIM] bf16 row-major; B^T: [N][KDIM] bf16 row-major.
// LDS layout: 128 rows x 8 chunks of 16B; slot (r,c) holds global chunk
// c ^ (r&7) of row r -> frag read at chunk g^(lc&7): 16 lanes cover all 32
// banks (2-way aliasing = free), and staging DMA stays lane-linear with
// permuted-contiguous 128B global segments.
template <int KDIM>
__device__ __forceinline__ void gemm_core(const ushort* __restrict__ Ab,
                                          const ushort* __restrict__ Bb,
                                          ushort* ldsA, ushort* ldsB,
                                          int bm0, int bn0,
                                          floatx4 (&acc)[4][4]) {
  const int t    = threadIdx.x;
  const int lane = t & 63;
  const int w    = t >> 6;
  const int wm   = w >> 1, wn = w & 1;
  const int lc   = lane & 15;
  const int q    = lane >> 4;          // k-group 0..3

  // staging: slot i = ro*256+t -> LDS row i>>3, chunk i&7; global source
  // row = ro*32 + (t>>3), chunk = (t&7) ^ ((t>>3)&7)
  const int arow   = t >> 3;
  const int achunk = (t & 7) ^ (arow & 7);
  const char* gA[4];
  const char* gB[4];
  char* lA[4];
  char* lB[4];
  #pragma unroll
  for (int ro = 0; ro < 4; ro++) {
    gA[ro] = (const char*)(Ab + (size_t)(bm0 + ro * 32 + arow) * KDIM) + achunk * 16;
    gB[ro] = (const char*)(Bb + (size_t)(bn0 + ro * 32 + arow) * KDIM) + achunk * 16;
    lA[ro] = (char*)ldsA + (ro * 256 + t) * 16;
    lB[ro] = (char*)ldsB + (ro * 256 + t) * 16;
  }

  // frag base byte-offsets: row=(w?*64+lc), substep s chunk = (s*4+q)^(lc&7);
  // frag i adds i*16 rows = i*2048 bytes (ds_read immediate offset).
  const int baseA0 = (wm * 64 + lc) * 128 + ((q    ) ^ (lc & 7)) * 16;
  const int baseA1 = (wm * 64 + lc) * 128 + ((q + 4) ^ (lc & 7)) * 16;
  const int baseB0 = (wn * 64 + lc) * 128 + ((q    ) ^ (lc & 7)) * 16;
  const int baseB1 = (wn * 64 + lc) * 128 + ((q + 4) ^ (lc & 7)) * 16;

  #pragma unroll
  for (int mi = 0; mi < 4; mi++)
    #pragma unroll
    for (int ni = 0; ni < 4; ni++)
      acc[mi][ni] = (floatx4){0.f, 0.f, 0.f, 0.f};

  for (int k0 = 0; k0 < KDIM; k0 += 64) {
    __syncthreads();                  // all waves done reading previous tile
    #pragma unroll
    for (int ro = 0; ro < 4; ro++) { async_copy16(gA[ro], lA[ro]); gA[ro] += 128; }
    #pragma unroll
    for (int ro = 0; ro < 4; ro++) { async_copy16(gB[ro], lB[ro]); gB[ro] += 128; }
    __syncthreads();                  // drains vmcnt(0): DMA complete

    short8 af[4], bfr[4];
    // substep 0 (k 0..31)
    #pragma unroll
    for (int i = 0; i < 4; i++) af[i]  = *(const short8*)((const char*)ldsA + baseA0 + i * 2048);
    #pragma unroll
    for (int i = 0; i < 4; i++) bfr[i] = *(const short8*)((const char*)ldsB + baseB0 + i * 2048);
    #pragma unroll
    for (int mi = 0; mi < 4; mi++)
      #pragma unroll
      for (int ni = 0; ni < 4; ni++)
        acc[mi][ni] = __builtin_amdgcn_mfma_f32_16x16x32_bf16(af[mi], bfr[ni],
                                                              acc[mi][ni], 0, 0, 0);
    // substep 1 (k 32..63)
    #pragma unroll
    for (int i = 0; i < 4; i++) af[i]  = *(const short8*)((const char*)ldsA + baseA1 + i * 2048);
    #pragma unroll
    for (int i = 0; i < 4; i++) bfr[i] = *(const short8*)((const char*)ldsB + baseB1 + i * 2048);
    #pragma unroll
    for (int mi = 0; mi < 4; mi++)
      #pragma unroll
      for (int ni = 0; ni < 4; ni++)
        acc[mi][ni] = __builtin_amdgcn_mfma_f32_16x16x32_bf16(af[mi], bfr[ni],
                                                              acc[mi][ni], 0, 0, 0);
  }
}

// GEMM1: P = exp(tanh(Q K + b)) in bf16; row sums of the bf16-rounded P via
// per-16-lane shuffle reduce + one atomicAdd per row-fragment.
__global__ void gemm_qk(const ushort* __restrict__ Q, const ushort* __restrict__ Kt,
                        const float* __restrict__ bias, ushort* __restrict__ P,
                        float* __restrict__ lsum) {
  __shared__ ushort ldsA[128 * 64];
  __shared__ ushort ldsB[128 * 64];
  const int z   = blockIdx.z;
  const int bm0 = blockIdx.y * 128;
  const int bn0 = blockIdx.x * 128;

  floatx4 acc[4][4];
  gemm_core<D_>(Q + (size_t)z * TQ_ * D_, Kt + (size_t)z * TK_ * D_,
                ldsA, ldsB, bm0, bn0, acc);

  const int lane = threadIdx.x & 63;
  const int w    = threadIdx.x >> 6;
  const int wm   = w >> 1, wn = w & 1;
  const int lc   = lane & 15;
  ushort* Pb = P + (size_t)z * TQ_ * TK_;
  float*  lz = lsum + z * TQ_;

  #pragma unroll
  for (int mi = 0; mi < 4; mi++) {
    int grow = bm0 + wm * 64 + mi * 16 + ((lane >> 4) << 2);  // + r
    float rs[4] = {0.f, 0.f, 0.f, 0.f};
    #pragma unroll
    for (int ni = 0; ni < 4; ni++) {
      int gcol = bn0 + wn * 64 + ni * 16 + lc;
      float bj = bias[gcol];
      #pragma unroll
      for (int r = 0; r < 4; r++) {
        float s = acc[mi][ni][r] + bj;
        // tanh(s) = 1 - 2/(e^{2s}+1); safe at +/-inf. exp(tanh) in [0.37,2.72]
        // => softmax needs no max subtraction.
        float tnh = 1.f - 2.f / (__expf(2.f * s) + 1.f);
        float p   = __expf(tnh);
        ushort pu = f2bf(p);
        Pb[(size_t)(grow + r) * TK_ + gcol] = pu;
        rs[r] += bf2f(pu);
      }
    }
    #pragma unroll
    for (int r = 0; r < 4; r++) {
      rs[r] += __shfl_xor(rs[r], 1, 64);
      rs[r] += __shfl_xor(rs[r], 2, 64);
      rs[r] += __shfl_xor(rs[r], 4, 64);
      rs[r] += __shfl_xor(rs[r], 8, 64);
    }
    if (lc == 0) {
      #pragma unroll
      for (int r = 0; r < 4; r++) atomicAdd(&lz[grow + r], rs[r]);
    }
  }
}

// GEMM2: out = (P Vt^T) / lsum, fp32 out
__global__ void gemm_pv(const ushort* __restrict__ P, const ushort* __restrict__ Vt,
                        const float* __restrict__ lsum, float* __restrict__ out) {
  __shared__ ushort ldsA[128 * 64];
  __shared__ ushort ldsB[128 * 64];
  const int z   = blockIdx.z;
  const int bm0 = blockIdx.y * 128;
  const int bn0 = blockIdx.x * 128;

  floatx4 acc[4][4];
  gemm_core<TK_>(P + (size_t)z * TQ_ * TK_, Vt + (size_t)z * DV_ * TK_,
                 ldsA, ldsB, bm0, bn0, acc);

  const int lane = threadIdx.x & 63;
  const int w    = threadIdx.x >> 6;
  const int wm   = w >> 1, wn = w & 1;
  const int lc   = lane & 15;
  float* ob = out + (size_t)z * TQ_ * DV_;
  const float* lz = lsum + z * TQ_;

  #pragma unroll
  for (int mi = 0; mi < 4; mi++) {
    int grow = bm0 + wm * 64 + mi * 16 + ((lane >> 4) << 2);
    float linv[4];
    #pragma unroll
    for (int r = 0; r < 4; r++) linv[r] = 1.f / lz[grow + r];
    #pragma unroll
    for (int ni = 0; ni < 4; ni++) {
      int gcol = bn0 + wn * 64 + ni * 16 + lc;
      #pragma unroll
      for (int r = 0; r < 4; r++)
        ob[(size_t)(grow + r) * DV_ + gcol] = acc[mi][ni][r] * linv[r];
    }
  }
}

// ---------------- launch ----------------
// Workspace layout (bytes):
//   qb   @ 0         : 8*2048*1024*2 = 33554432   (Q bf16)
//   ktb  @ 33554432  : 33554432                   (K^T bf16, [TK][D])
//   vtb  @ 67108864  : 33554432                   (V^T bf16, [DV][TK])
//   P    @ 100663296 : 8*2048*2048*2 = 67108864   (exp(tanh(S)) bf16)
//   lsum @ 167772160 : 8*2048*4      = 65536      (softmax denominators)
// Total: 167837696 bytes (~160 MB)

extern "C" void kernel_launch(void* const* d_in, const int* in_sizes, int n_in,
                              void* d_out, int out_size, void* d_ws, size_t ws_size,
                              hipStream_t stream) {
  const float* q    = (const float*)d_in[0];
  const float* k    = (const float*)d_in[1];
  const float* v    = (const float*)d_in[2];
  const float* bias = (const float*)d_in[3];
  float* out = (float*)d_out;

  char* ws = (char*)d_ws;
  ushort* qb   = (ushort*)(ws);
  ushort* ktb  = (ushort*)(ws + 33554432);
  ushort* vtb  = (ushort*)(ws + 67108864);
  ushort* P    = (ushort*)(ws + 100663296);
  float*  lsum = (float*)(ws + 167772160);

  hipMemsetAsync(lsum, 0, B_ * TQ_ * sizeof(float), stream);

  int n4q = B_ * TQ_ * D_ / 4;
  cvt_bf16<<<dim3(n4q / 256), dim3(256), 0, stream>>>((const float4*)q, (ushort4*)qb, n4q);
  // k: [D][TK] -> ktb [TK][D]
  transpose_cvt64<<<dim3(TK_ / 64, D_ / 64, B_), dim3(256), 0, stream>>>(k, ktb, D_, TK_);
  // v: [TK][DV] -> vtb [DV][TK]
  transpose_cvt64<<<dim3(DV_ / 64, TK_ / 64, B_), dim3(256), 0, stream>>>(v, vtb, TK_, DV_);

  gemm_qk<<<dim3(TK_ / 128, TQ_ / 128, B_), dim3(256), 0, stream>>>(qb, ktb, bias, P, lsum);
  gemm_pv<<<dim3(DV_ / 128, TQ_ / 128, B_), dim3(256), 0, stream>>>(P, vtb, lsum, out);
}

// Round 3
// 415.000 us; speedup vs baseline: 1.3348x; 1.3348x over previous
//
#include <hip/hip_runtime.h>
#include <hip/hip_bf16.h>
#include <stdint.h>

// Problem constants (reference: B,TQ,TK,D,DV = 8,2048,2048,1024,1024)
#define B_  8
#define TQ_ 2048
#define TK_ 2048
#define D_  1024
#define DV_ 1024

typedef __attribute__((ext_vector_type(8))) short  short8;
typedef __attribute__((ext_vector_type(4))) float  floatx4;

__device__ __forceinline__ void async_copy16(const void* g, void* l) {
  // 16B-per-lane global->LDS DMA. LDS dest is wave-uniform base + lane*16.
  __builtin_amdgcn_global_load_lds(
      (const __attribute__((address_space(1))) unsigned int*)g,
      (__attribute__((address_space(3))) unsigned int*)l,
      16, 0, 0);
}

__device__ __forceinline__ ushort f2bf(float f) {
  union { __hip_bfloat16 b; ushort u; } cv;
  cv.b = __float2bfloat16(f);
  return cv.u;
}

__device__ __forceinline__ float bf2f(ushort u) {
  union { ushort u; __hip_bfloat16 b; } cv;
  cv.u = u;
  return __bfloat162float(cv.b);
}

// ---------------- conversion kernels ----------------

// fp32 -> bf16, same layout, 4 elems/thread
__global__ void cvt_bf16(const float4* __restrict__ in, ushort4* __restrict__ out, int n4) {
  int i = blockIdx.x * 256 + threadIdx.x;
  if (i < n4) {
    float4 f = in[i];
    ushort4 o;
    o.x = f2bf(f.x); o.y = f2bf(f.y); o.z = f2bf(f.z); o.w = f2bf(f.w);
    out[i] = o;
  }
}

// in: [z][R][C] fp32 -> out: [z][C][R] bf16. 64x64 tiles, float4 loads,
// ushort4 stores.
__global__ void transpose_cvt64(const float* __restrict__ in, ushort* __restrict__ out,
                                int R, int C) {
  __shared__ float tile[64][65];
  const int t  = threadIdx.x;            // 256
  const int c0 = blockIdx.x * 64, r0 = blockIdx.y * 64;
  const size_t z = (size_t)blockIdx.z * R * C;
  {
    const int row = t >> 4, col = (t & 15) * 4;
    #pragma unroll
    for (int ro = 0; ro < 4; ro++) {
      const float4 f = *(const float4*)&in[z + (size_t)(r0 + ro * 16 + row) * C + c0 + col];
      tile[ro * 16 + row][col + 0] = f.x;
      tile[ro * 16 + row][col + 1] = f.y;
      tile[ro * 16 + row][col + 2] = f.z;
      tile[ro * 16 + row][col + 3] = f.w;
    }
  }
  __syncthreads();
  {
    const int c = t >> 4, rg = (t & 15) * 4;
    #pragma unroll
    for (int ro = 0; ro < 4; ro++) {
      const int cc = ro * 16 + c;
      ushort4 o;
      o.x = f2bf(tile[rg + 0][cc]);
      o.y = f2bf(tile[rg + 1][cc]);
      o.z = f2bf(tile[rg + 2][cc]);
      o.w = f2bf(tile[rg + 3][cc]);
      *(ushort4*)&out[z + (size_t)(c0 + cc) * R + r0 + rg] = o;
    }
  }
}

// ---------------- GEMM core (BK=32, round-1 structure + 2-way swizzle) -----
// C[128x128]/block, 256 thr = 4 waves 2x2, each wave 64x64 = 4x4 tiles of
// mfma_f32_16x16x32_bf16. A: [M][KDIM] bf16 row-major; B^T: [N][KDIM] bf16
// row-major. LDS per matrix: 128 rows x 4 chunks of 16B = 8 KB.
// Swizzle: slot (r, c) holds global chunk c ^ ((r>>1)&3). ds_read_b128 by a
// quad-group (16 lanes, rows base..base+15) then hits every 4-bank group
// exactly 2x -> 2-way aliasing = free (m136). Staging DMA stays lane-linear;
// global chunks are permuted only within each row's 64B segment (coalesced).
template <int KDIM>
__device__ __forceinline__ void gemm_core(const ushort* __restrict__ Ab,
                                          const ushort* __restrict__ Bb,
                                          ushort* ldsA, ushort* ldsB,
                                          int bm0, int bn0,
                                          floatx4 (&acc)[4][4]) {
  const int t    = threadIdx.x;
  const int lane = t & 63;
  const int w    = t >> 6;
  const int wm   = w >> 1, wn = w & 1;
  const int lc   = lane & 15;
  const int q    = lane >> 4;          // k-group 0..3

  // staging: slot t -> row t>>2, slot-chunk t&3, global chunk (t&3)^((t>>3)&3)
  // (rows 64..127 use the same XOR term: ((64+r)>>1)&3 == (r>>1)&3).
  const int achunk = (t & 3) ^ ((t >> 3) & 3);
  const char* ga0 = (const char*)(Ab + (size_t)(bm0 + (t >> 2)) * KDIM) + achunk * 16;
  const char* ga1 = ga0 + (size_t)64 * KDIM * 2;
  const char* gb0 = (const char*)(Bb + (size_t)(bn0 + (t >> 2)) * KDIM) + achunk * 16;
  const char* gb1 = gb0 + (size_t)64 * KDIM * 2;
  char* la0 = (char*)ldsA + t * 16;
  char* la1 = (char*)ldsA + 4096 + t * 16;
  char* lb0 = (char*)ldsB + t * 16;
  char* lb1 = (char*)ldsB + 4096 + t * 16;

  // frag bases: row = w?*64 + lc (+ i*16 per frag; the XOR term is invariant
  // under +16 rows, so frag i is base + i*1024 -> ds_read immediate offsets).
  const int rA = wm * 64 + lc;
  const int rB = wn * 64 + lc;
  const int baseA = rA * 64 + (q ^ ((rA >> 1) & 3)) * 16;
  const int baseB = rB * 64 + (q ^ ((rB >> 1) & 3)) * 16;

  #pragma unroll
  for (int mi = 0; mi < 4; mi++)
    #pragma unroll
    for (int ni = 0; ni < 4; ni++)
      acc[mi][ni] = (floatx4){0.f, 0.f, 0.f, 0.f};

  for (int k0 = 0; k0 < KDIM; k0 += 32) {
    __syncthreads();                  // all waves done reading previous tile
    async_copy16(ga0, la0);
    async_copy16(ga1, la1);
    async_copy16(gb0, lb0);
    async_copy16(gb1, lb1);
    ga0 += 64; ga1 += 64; gb0 += 64; gb1 += 64;
    __syncthreads();                  // drains vmcnt(0): DMA complete

    short8 af[4], bfr[4];
    #pragma unroll
    for (int i = 0; i < 4; i++) af[i]  = *(const short8*)((const char*)ldsA + baseA + i * 1024);
    #pragma unroll
    for (int i = 0; i < 4; i++) bfr[i] = *(const short8*)((const char*)ldsB + baseB + i * 1024);
    #pragma unroll
    for (int mi = 0; mi < 4; mi++)
      #pragma unroll
      for (int ni = 0; ni < 4; ni++)
        acc[mi][ni] = __builtin_amdgcn_mfma_f32_16x16x32_bf16(af[mi], bfr[ni],
                                                              acc[mi][ni], 0, 0, 0);
  }
}

// GEMM1: P = exp(tanh(Q K + b)) in bf16; row sums of the bf16-rounded P via
// per-16-lane shuffle reduce + one atomicAdd per row-fragment.
__global__ void gemm_qk(const ushort* __restrict__ Q, const ushort* __restrict__ Kt,
                        const float* __restrict__ bias, ushort* __restrict__ P,
                        float* __restrict__ lsum) {
  __shared__ ushort ldsA[128 * 32];
  __shared__ ushort ldsB[128 * 32];
  const int z   = blockIdx.z;
  const int bm0 = blockIdx.y * 128;
  const int bn0 = blockIdx.x * 128;

  floatx4 acc[4][4];
  gemm_core<D_>(Q + (size_t)z * TQ_ * D_, Kt + (size_t)z * TK_ * D_,
                ldsA, ldsB, bm0, bn0, acc);

  const int lane = threadIdx.x & 63;
  const int w    = threadIdx.x >> 6;
  const int wm   = w >> 1, wn = w & 1;
  const int lc   = lane & 15;
  ushort* Pb = P + (size_t)z * TQ_ * TK_;
  float*  lz = lsum + z * TQ_;

  #pragma unroll
  for (int mi = 0; mi < 4; mi++) {
    int grow = bm0 + wm * 64 + mi * 16 + ((lane >> 4) << 2);  // + r
    float rs[4] = {0.f, 0.f, 0.f, 0.f};
    #pragma unroll
    for (int ni = 0; ni < 4; ni++) {
      int gcol = bn0 + wn * 64 + ni * 16 + lc;
      float bj = bias[gcol];
      #pragma unroll
      for (int r = 0; r < 4; r++) {
        float s = acc[mi][ni][r] + bj;
        // tanh(s) = 1 - 2/(e^{2s}+1); safe at +/-inf. exp(tanh) in [0.37,2.72]
        // => softmax needs no max subtraction.
        float tnh = 1.f - 2.f / (__expf(2.f * s) + 1.f);
        float p   = __expf(tnh);
        ushort pu = f2bf(p);
        Pb[(size_t)(grow + r) * TK_ + gcol] = pu;
        rs[r] += bf2f(pu);
      }
    }
    #pragma unroll
    for (int r = 0; r < 4; r++) {
      rs[r] += __shfl_xor(rs[r], 1, 64);
      rs[r] += __shfl_xor(rs[r], 2, 64);
      rs[r] += __shfl_xor(rs[r], 4, 64);
      rs[r] += __shfl_xor(rs[r], 8, 64);
    }
    if (lc == 0) {
      #pragma unroll
      for (int r = 0; r < 4; r++) atomicAdd(&lz[grow + r], rs[r]);
    }
  }
}

// GEMM2: out = (P Vt^T) / lsum, fp32 out
__global__ void gemm_pv(const ushort* __restrict__ P, const ushort* __restrict__ Vt,
                        const float* __restrict__ lsum, float* __restrict__ out) {
  __shared__ ushort ldsA[128 * 32];
  __shared__ ushort ldsB[128 * 32];
  const int z   = blockIdx.z;
  const int bm0 = blockIdx.y * 128;
  const int bn0 = blockIdx.x * 128;

  floatx4 acc[4][4];
  gemm_core<TK_>(P + (size_t)z * TQ_ * TK_, Vt + (size_t)z * DV_ * TK_,
                 ldsA, ldsB, bm0, bn0, acc);

  const int lane = threadIdx.x & 63;
  const int w    = threadIdx.x >> 6;
  const int wm   = w >> 1, wn = w & 1;
  const int lc   = lane & 15;
  float* ob = out + (size_t)z * TQ_ * DV_;
  const float* lz = lsum + z * TQ_;

  #pragma unroll
  for (int mi = 0; mi < 4; mi++) {
    int grow = bm0 + wm * 64 + mi * 16 + ((lane >> 4) << 2);
    float linv[4];
    #pragma unroll
    for (int r = 0; r < 4; r++) linv[r] = 1.f / lz[grow + r];
    #pragma unroll
    for (int ni = 0; ni < 4; ni++) {
      int gcol = bn0 + wn * 64 + ni * 16 + lc;
      #pragma unroll
      for (int r = 0; r < 4; r++)
        ob[(size_t)(grow + r) * DV_ + gcol] = acc[mi][ni][r] * linv[r];
    }
  }
}

// ---------------- launch ----------------
// Workspace layout (bytes):
//   qb   @ 0         : 8*2048*1024*2 = 33554432   (Q bf16)
//   ktb  @ 33554432  : 33554432                   (K^T bf16, [TK][D])
//   vtb  @ 67108864  : 33554432                   (V^T bf16, [DV][TK])
//   P    @ 100663296 : 8*2048*2048*2 = 67108864   (exp(tanh(S)) bf16)
//   lsum @ 167772160 : 8*2048*4      = 65536      (softmax denominators)
// Total: 167837696 bytes (~160 MB)

extern "C" void kernel_launch(void* const* d_in, const int* in_sizes, int n_in,
                              void* d_out, int out_size, void* d_ws, size_t ws_size,
                              hipStream_t stream) {
  const float* q    = (const float*)d_in[0];
  const float* k    = (const float*)d_in[1];
  const float* v    = (const float*)d_in[2];
  const float* bias = (const float*)d_in[3];
  float* out = (float*)d_out;

  char* ws = (char*)d_ws;
  ushort* qb   = (ushort*)(ws);
  ushort* ktb  = (ushort*)(ws + 33554432);
  ushort* vtb  = (ushort*)(ws + 67108864);
  ushort* P    = (ushort*)(ws + 100663296);
  float*  lsum = (float*)(ws + 167772160);

  hipMemsetAsync(lsum, 0, B_ * TQ_ * sizeof(float), stream);

  int n4q = B_ * TQ_ * D_ / 4;
  cvt_bf16<<<dim3(n4q / 256), dim3(256), 0, stream>>>((const float4*)q, (ushort4*)qb, n4q);
  // k: [D][TK] -> ktb [TK][D]
  transpose_cvt64<<<dim3(TK_ / 64, D_ / 64, B_), dim3(256), 0, stream>>>(k, ktb, D_, TK_);
  // v: [TK][DV] -> vtb [DV][TK]
  transpose_cvt64<<<dim3(DV_ / 64, TK_ / 64, B_), dim3(256), 0, stream>>>(v, vtb, TK_, DV_);

  gemm_qk<<<dim3(TK_ / 128, TQ_ / 128, B_), dim3(256), 0, stream>>>(qb, ktb, bias, P, lsum);
  gemm_pv<<<dim3(DV_ / 128, TQ_ / 128, B_), dim3(256), 0, stream>>>(P, vtb, lsum, out);
}

// Round 4
// 411.298 us; speedup vs baseline: 1.3469x; 1.0090x over previous
//
#include <hip/hip_runtime.h>
#include <hip/hip_bf16.h>
#include <stdint.h>

// Problem constants (reference: B,TQ,TK,D,DV = 8,2048,2048,1024,1024)
#define B_  8
#define TQ_ 2048
#define TK_ 2048
#define D_  1024
#define DV_ 1024

typedef __attribute__((ext_vector_type(8))) short  short8;
typedef __attribute__((ext_vector_type(4))) float  floatx4;

__device__ __forceinline__ void async_copy16(const void* g, void* l) {
  // 16B-per-lane global->LDS DMA. LDS dest is wave-uniform base + lane*16.
  __builtin_amdgcn_global_load_lds(
      (const __attribute__((address_space(1))) unsigned int*)g,
      (__attribute__((address_space(3))) unsigned int*)l,
      16, 0, 0);
}

__device__ __forceinline__ ushort f2bf(float f) {
  union { __hip_bfloat16 b; ushort u; } cv;
  cv.b = __float2bfloat16(f);
  return cv.u;
}

__device__ __forceinline__ float bf2f(ushort u) {
  union { ushort u; __hip_bfloat16 b; } cv;
  cv.u = u;
  return __bfloat162float(cv.b);
}

// ---------------- fused prep kernel ----------------
// grid (32,16,24), block 256.
//   z  0..7 : q fp32 -> bf16 (same layout), batch z
//   z  8..15: k [D][TK] -> ktb [TK][D], batch z-8   (64x64 tiled transpose)
//   z 16..23: v [TK][DV] -> vtb [DV][TK], batch z-16

__device__ __forceinline__ void transpose_body(const float* __restrict__ in,
                                               ushort* __restrict__ out,
                                               int R, int C, int r0, int c0,
                                               float (*tile)[65]) {
  const int t = threadIdx.x;
  {
    const int row = t >> 4, col = (t & 15) * 4;
    #pragma unroll
    for (int ro = 0; ro < 4; ro++) {
      const float4 f = *(const float4*)&in[(size_t)(r0 + ro * 16 + row) * C + c0 + col];
      tile[ro * 16 + row][col + 0] = f.x;
      tile[ro * 16 + row][col + 1] = f.y;
      tile[ro * 16 + row][col + 2] = f.z;
      tile[ro * 16 + row][col + 3] = f.w;
    }
  }
  __syncthreads();
  {
    const int c = t >> 4, rg = (t & 15) * 4;
    #pragma unroll
    for (int ro = 0; ro < 4; ro++) {
      const int cc = ro * 16 + c;
      ushort4 o;
      o.x = f2bf(tile[rg + 0][cc]);
      o.y = f2bf(tile[rg + 1][cc]);
      o.z = f2bf(tile[rg + 2][cc]);
      o.w = f2bf(tile[rg + 3][cc]);
      *(ushort4*)&out[(size_t)(c0 + cc) * R + r0 + rg] = o;
    }
  }
}

__global__ void prep(const float* __restrict__ q, const float* __restrict__ k,
                     const float* __restrict__ v, ushort* __restrict__ qb,
                     ushort* __restrict__ ktb, ushort* __restrict__ vtb) {
  __shared__ float tile[64][65];
  const int task = blockIdx.z >> 3;
  const int z    = blockIdx.z & 7;
  if (task == 0) {
    // q cvt: per batch 2M elems = 512 blocks x 256 thr x 4 x float4
    const float4* in  = (const float4*)(q + (size_t)z * TQ_ * D_);
    ushort4*      oup = (ushort4*)(qb + (size_t)z * TQ_ * D_);
    const int i0 = (blockIdx.y * 32 + blockIdx.x) * 1024 + threadIdx.x;
    #pragma unroll
    for (int it = 0; it < 4; it++) {
      const int i = i0 + it * 256;
      float4 f = in[i];
      ushort4 o;
      o.x = f2bf(f.x); o.y = f2bf(f.y); o.z = f2bf(f.z); o.w = f2bf(f.w);
      oup[i] = o;
    }
  } else if (task == 1) {
    // k: R=D_=1024 rows, C=TK_=2048 cols; c-tiles 32 (x), r-tiles 16 (y)
    transpose_body(k + (size_t)z * D_ * TK_, ktb + (size_t)z * TK_ * D_,
                   D_, TK_, blockIdx.y * 64, blockIdx.x * 64, tile);
  } else {
    // v: R=TK_=2048 rows, C=DV_=1024 cols; r-tiles 32 (x), c-tiles 16 (y)
    transpose_body(v + (size_t)z * TK_ * DV_, vtb + (size_t)z * DV_ * TK_,
                   TK_, DV_, blockIdx.x * 64, blockIdx.y * 64, tile);
  }
}

// ---------------- GEMM core (BK=32, double-buffered LDS, 2-way swizzle) ----
// C[128x128]/block, 256 thr = 4 waves 2x2, each wave 64x64 = 4x4 tiles of
// mfma_f32_16x16x32_bf16. A: [M][KDIM] bf16 row-major; B^T: [N][KDIM] bf16
// row-major. LDS per matrix: 2 buffers x (128 rows x 4 chunks of 16B) = 16 KB.
// Pipeline: prologue DMA tile0 -> buf0; each step: barrier (drains prev DMA,
// releases other buffer) -> DMA tile k+1 into other buffer -> compute tile k.
// The vmcnt(0) drain at the next barrier lands AFTER a full compute phase, so
// the global->LDS latency is hidden (vs round-3's exposed wait).
// Swizzle (verified round 3, conflicts=0): slot (r,c) holds chunk c^((r>>1)&3).
template <int KDIM>
__device__ __forceinline__ void gemm_core(const ushort* __restrict__ Ab,
                                          const ushort* __restrict__ Bb,
                                          ushort* ldsA, ushort* ldsB,  // 2x8KB each
                                          int bm0, int bn0,
                                          floatx4 (&acc)[4][4]) {
  const int t    = threadIdx.x;
  const int lane = t & 63;
  const int w    = t >> 6;
  const int wm   = w >> 1, wn = w & 1;
  const int lc   = lane & 15;
  const int q    = lane >> 4;          // k-group 0..3

  // staging: slot t -> row t>>2, slot-chunk t&3, global chunk (t&3)^((t>>3)&3)
  const int achunk = (t & 3) ^ ((t >> 3) & 3);
  const char* ga0 = (const char*)(Ab + (size_t)(bm0 + (t >> 2)) * KDIM) + achunk * 16;
  const char* ga1 = ga0 + (size_t)64 * KDIM * 2;
  const char* gb0 = (const char*)(Bb + (size_t)(bn0 + (t >> 2)) * KDIM) + achunk * 16;
  const char* gb1 = gb0 + (size_t)64 * KDIM * 2;
  char* la0 = (char*)ldsA + t * 16;            // buffer-0 addresses
  char* la1 = (char*)ldsA + 4096 + t * 16;
  char* lb0 = (char*)ldsB + t * 16;
  char* lb1 = (char*)ldsB + 4096 + t * 16;

  // frag bases within an 8 KB buffer (XOR term invariant under +16 rows).
  const int rA = wm * 64 + lc;
  const int rB = wn * 64 + lc;
  const int baseA = rA * 64 + (q ^ ((rA >> 1) & 3)) * 16;
  const int baseB = rB * 64 + (q ^ ((rB >> 1) & 3)) * 16;

  #pragma unroll
  for (int mi = 0; mi < 4; mi++)
    #pragma unroll
    for (int ni = 0; ni < 4; ni++)
      acc[mi][ni] = (floatx4){0.f, 0.f, 0.f, 0.f};

  // prologue: stage tile 0 into buffer 0
  async_copy16(ga0, la0);
  async_copy16(ga1, la1);
  async_copy16(gb0, lb0);
  async_copy16(gb1, lb1);
  ga0 += 64; ga1 += 64; gb0 += 64; gb1 += 64;

  int cur = 0;  // byte offset of current buffer: 0 or 8192
  for (int k0 = 0; k0 < KDIM; k0 += 32) {
    __syncthreads();   // drains DMA of buf[cur]; releases buf[cur^8192] readers
    if (k0 + 32 < KDIM) {
      const int nxt = cur ^ 8192;
      async_copy16(ga0, la0 + nxt);
      async_copy16(ga1, la1 + nxt);
      async_copy16(gb0, lb0 + nxt);
      async_copy16(gb1, lb1 + nxt);
      ga0 += 64; ga1 += 64; gb0 += 64; gb1 += 64;
    }

    short8 af[4], bfr[4];
    #pragma unroll
    for (int i = 0; i < 4; i++)
      af[i]  = *(const short8*)((const char*)ldsA + cur + baseA + i * 1024);
    #pragma unroll
    for (int i = 0; i < 4; i++)
      bfr[i] = *(const short8*)((const char*)ldsB + cur + baseB + i * 1024);
    #pragma unroll
    for (int mi = 0; mi < 4; mi++)
      #pragma unroll
      for (int ni = 0; ni < 4; ni++)
        acc[mi][ni] = __builtin_amdgcn_mfma_f32_16x16x32_bf16(af[mi], bfr[ni],
                                                              acc[mi][ni], 0, 0, 0);
    cur ^= 8192;
  }
}

// GEMM1: P = exp(tanh(Q K + b)) in bf16; row sums of the bf16-rounded P via
// per-16-lane shuffle reduce + one atomicAdd per row-fragment.
__global__ void gemm_qk(const ushort* __restrict__ Q, const ushort* __restrict__ Kt,
                        const float* __restrict__ bias, ushort* __restrict__ P,
                        float* __restrict__ lsum) {
  __shared__ ushort ldsA[2 * 128 * 32];
  __shared__ ushort ldsB[2 * 128 * 32];
  const int z   = blockIdx.z;
  const int bm0 = blockIdx.y * 128;
  const int bn0 = blockIdx.x * 128;

  floatx4 acc[4][4];
  gemm_core<D_>(Q + (size_t)z * TQ_ * D_, Kt + (size_t)z * TK_ * D_,
                ldsA, ldsB, bm0, bn0, acc);

  const int lane = threadIdx.x & 63;
  const int w    = threadIdx.x >> 6;
  const int wm   = w >> 1, wn = w & 1;
  const int lc   = lane & 15;
  ushort* Pb = P + (size_t)z * TQ_ * TK_;
  float*  lz = lsum + z * TQ_;

  #pragma unroll
  for (int mi = 0; mi < 4; mi++) {
    int grow = bm0 + wm * 64 + mi * 16 + ((lane >> 4) << 2);  // + r
    float rs[4] = {0.f, 0.f, 0.f, 0.f};
    #pragma unroll
    for (int ni = 0; ni < 4; ni++) {
      int gcol = bn0 + wn * 64 + ni * 16 + lc;
      float bj = bias[gcol];
      #pragma unroll
      for (int r = 0; r < 4; r++) {
        float s = acc[mi][ni][r] + bj;
        // tanh(s) = 1 - 2/(e^{2s}+1); safe at +/-inf. exp(tanh) in [0.37,2.72]
        // => softmax needs no max subtraction.
        float tnh = 1.f - 2.f / (__expf(2.f * s) + 1.f);
        float p   = __expf(tnh);
        ushort pu = f2bf(p);
        Pb[(size_t)(grow + r) * TK_ + gcol] = pu;
        rs[r] += bf2f(pu);
      }
    }
    #pragma unroll
    for (int r = 0; r < 4; r++) {
      rs[r] += __shfl_xor(rs[r], 1, 64);
      rs[r] += __shfl_xor(rs[r], 2, 64);
      rs[r] += __shfl_xor(rs[r], 4, 64);
      rs[r] += __shfl_xor(rs[r], 8, 64);
    }
    if (lc == 0) {
      #pragma unroll
      for (int r = 0; r < 4; r++) atomicAdd(&lz[grow + r], rs[r]);
    }
  }
}

// GEMM2: out = (P Vt^T) / lsum, fp32 out
__global__ void gemm_pv(const ushort* __restrict__ P, const ushort* __restrict__ Vt,
                        const float* __restrict__ lsum, float* __restrict__ out) {
  __shared__ ushort ldsA[2 * 128 * 32];
  __shared__ ushort ldsB[2 * 128 * 32];
  const int z   = blockIdx.z;
  const int bm0 = blockIdx.y * 128;
  const int bn0 = blockIdx.x * 128;

  floatx4 acc[4][4];
  gemm_core<TK_>(P + (size_t)z * TQ_ * TK_, Vt + (size_t)z * DV_ * TK_,
                 ldsA, ldsB, bm0, bn0, acc);

  const int lane = threadIdx.x & 63;
  const int w    = threadIdx.x >> 6;
  const int wm   = w >> 1, wn = w & 1;
  const int lc   = lane & 15;
  float* ob = out + (size_t)z * TQ_ * DV_;
  const float* lz = lsum + z * TQ_;

  #pragma unroll
  for (int mi = 0; mi < 4; mi++) {
    int grow = bm0 + wm * 64 + mi * 16 + ((lane >> 4) << 2);
    float linv[4];
    #pragma unroll
    for (int r = 0; r < 4; r++) linv[r] = 1.f / lz[grow + r];
    #pragma unroll
    for (int ni = 0; ni < 4; ni++) {
      int gcol = bn0 + wn * 64 + ni * 16 + lc;
      #pragma unroll
      for (int r = 0; r < 4; r++)
        ob[(size_t)(grow + r) * DV_ + gcol] = acc[mi][ni][r] * linv[r];
    }
  }
}

// ---------------- launch ----------------
// Workspace layout (bytes):
//   qb   @ 0         : 8*2048*1024*2 = 33554432   (Q bf16)
//   ktb  @ 33554432  : 33554432                   (K^T bf16, [TK][D])
//   vtb  @ 67108864  : 33554432                   (V^T bf16, [DV][TK])
//   P    @ 100663296 : 8*2048*2048*2 = 67108864   (exp(tanh(S)) bf16)
//   lsum @ 167772160 : 8*2048*4      = 65536      (softmax denominators)
// Total: 167837696 bytes (~160 MB)

extern "C" void kernel_launch(void* const* d_in, const int* in_sizes, int n_in,
                              void* d_out, int out_size, void* d_ws, size_t ws_size,
                              hipStream_t stream) {
  const float* q    = (const float*)d_in[0];
  const float* k    = (const float*)d_in[1];
  const float* v    = (const float*)d_in[2];
  const float* bias = (const float*)d_in[3];
  float* out = (float*)d_out;

  char* ws = (char*)d_ws;
  ushort* qb   = (ushort*)(ws);
  ushort* ktb  = (ushort*)(ws + 33554432);
  ushort* vtb  = (ushort*)(ws + 67108864);
  ushort* P    = (ushort*)(ws + 100663296);
  float*  lsum = (float*)(ws + 167772160);

  hipMemsetAsync(lsum, 0, B_ * TQ_ * sizeof(float), stream);

  prep<<<dim3(32, 16, 24), dim3(256), 0, stream>>>(q, k, v, qb, ktb, vtb);

  gemm_qk<<<dim3(TK_ / 128, TQ_ / 128, B_), dim3(256), 0, stream>>>(qb, ktb, bias, P, lsum);
  gemm_pv<<<dim3(DV_ / 128, TQ_ / 128, B_), dim3(256), 0, stream>>>(P, vtb, lsum, out);
}